// Round 2
// baseline (258.531 us; speedup 1.0000x reference)
//
#include <hip/hip_runtime.h>
#include <math.h>

#define B_ 32768
#define D_ 512
#define E_ 64
#define K_ 4
#define H_ 5376
#define H4_ (H_ / 4)

typedef float f32x4 __attribute__((ext_vector_type(4)));

// Fused: gating GEMMs (f64 accum) + top-5 + softmax gates + importance/load
// partials + output dispatch (out[b,:] = sum_k g_k * ctx[idx_k,:]).
// Block = 256 threads handles 64 tokens. Thread (ti,te) = (t>>4, t&15) owns
// tokens {ti,ti+16,ti+32,ti+48} x experts {4te..4te+3}.
__global__ __launch_bounds__(256) void gate_out_kernel(
    const float* __restrict__ x,
    const float* __restrict__ wgate,
    const float* __restrict__ wnoise,
    const float* __restrict__ noise,
    const float* __restrict__ ctx,
    float* __restrict__ out,
    float* __restrict__ g_imp,
    float* __restrict__ g_load)
{
    __shared__ float4 xs4[64 * 17];   // x tile [64 tok][64 d], row padded to 17 float4 (bank spread)
    __shared__ float4 wg4[64 * 16];   // w_gate tile [64 d][64 e]
    __shared__ float4 wn4[64 * 16];   // w_noise tile
    __shared__ float  s_imp[E_];
    __shared__ float  s_load[E_];
    __shared__ int    s_idx[64][4];
    __shared__ float  s_g[64][4];

    const int t  = threadIdx.x;
    const int te = t & 15;
    const int ti = t >> 4;
    const int b0 = blockIdx.x * 64;

    if (t < E_) { s_imp[t] = 0.0f; s_load[t] = 0.0f; }

    double acc_c[4][4];
    double acc_n[4][4];
#pragma unroll
    for (int q = 0; q < 4; ++q)
#pragma unroll
        for (int j = 0; j < 4; ++j) { acc_c[q][j] = 0.0; acc_n[q][j] = 0.0; }

    for (int kd = 0; kd < D_; kd += 64) {
        __syncthreads();   // protect LDS buffers from previous iteration's readers
#pragma unroll
        for (int r = 0; r < 4; ++r) {
            int f   = t + 256 * r;
            int row = f >> 4;
            int c4  = f & 15;
            xs4[row * 17 + c4] = *(const float4*)&x[(size_t)(b0 + row) * D_ + kd + c4 * 4];
            wg4[row * 16 + c4] = *(const float4*)&wgate[(size_t)(kd + row) * E_ + c4 * 4];
            wn4[row * 16 + c4] = *(const float4*)&wnoise[(size_t)(kd + row) * E_ + c4 * 4];
        }
        __syncthreads();
#pragma unroll 4
        for (int j4 = 0; j4 < 16; ++j4) {
            float4 xa[4];
#pragma unroll
            for (int q = 0; q < 4; ++q) xa[q] = xs4[(ti + 16 * q) * 17 + j4];
#pragma unroll
            for (int jj = 0; jj < 4; ++jj) {
                float4 wgv = wg4[(4 * j4 + jj) * 16 + te];
                float4 wnv = wn4[(4 * j4 + jj) * 16 + te];
                double wgd[4] = { (double)wgv.x, (double)wgv.y, (double)wgv.z, (double)wgv.w };
                double wnd[4] = { (double)wnv.x, (double)wnv.y, (double)wnv.z, (double)wnv.w };
#pragma unroll
                for (int q = 0; q < 4; ++q) {
                    double xv = (double)((const float*)&xa[q])[jj];
#pragma unroll
                    for (int j = 0; j < 4; ++j) {
                        acc_c[q][j] = fma(xv, wgd[j], acc_c[q][j]);
                        acc_n[q][j] = fma(xv, wnd[j], acc_n[q][j]);
                    }
                }
            }
        }
    }

    // ---- per-token post-processing: softplus, noisy logits, top-5, gates, load ----
    float loadacc[4] = {0.f, 0.f, 0.f, 0.f};

#pragma unroll 1
    for (int q = 0; q < 4; ++q) {
        int li = ti + 16 * q;   // local token
        int b  = b0 + li;       // global token
        float4 nz = *(const float4*)&noise[(size_t)b * E_ + 4 * te];
        double sd[4], ny[4];
#pragma unroll
        for (int j = 0; j < 4; ++j) {
            double z  = acc_n[q][j];
            double sp = (z > 30.0) ? z : log1p(exp(z));
            sd[j] = sp + 0.01;
            ny[j] = acc_c[q][j] + (double)((const float*)&nz)[j] * sd[j];
        }
        // top-5 across the token's 64 experts (spread over 16 contiguous lanes x 4 regs)
        double v[4] = { ny[0], ny[1], ny[2], ny[3] };
        double topv[5]; int topi[5];
#pragma unroll 1
        for (int s = 0; s < 5; ++s) {
            double bm = v[0]; int bj = 0;
#pragma unroll
            for (int j = 1; j < 4; ++j) if (v[j] > bm) { bm = v[j]; bj = j; }
            int be = 4 * te + bj;
#pragma unroll
            for (int off = 1; off < 16; off <<= 1) {
                double om = __shfl_xor(bm, off, 64);
                int    oe = __shfl_xor(be, off, 64);
                if (om > bm || (om == bm && oe < be)) { bm = om; be = oe; }
            }
            topv[s] = bm; topi[s] = be;
            if ((be >> 2) == te) v[be & 3] = -1.0e300;   // remove winner from owner lane
        }
        // softmax over top-4
        double m0 = topv[0];
        double e0 = exp(topv[0] - m0), e1 = exp(topv[1] - m0),
               e2 = exp(topv[2] - m0), e3 = exp(topv[3] - m0);
        double inv = 1.0 / (e0 + e1 + e2 + e3);
        float g0 = (float)(e0 * inv), g1 = (float)(e1 * inv),
              g2 = (float)(e2 * inv), g3 = (float)(e3 * inv);
        if (te == 0) {
            s_idx[li][0] = topi[0]; s_idx[li][1] = topi[1];
            s_idx[li][2] = topi[2]; s_idx[li][3] = topi[3];
            s_g[li][0] = g0; s_g[li][1] = g1; s_g[li][2] = g2; s_g[li][3] = g3;
            atomicAdd(&s_imp[topi[0]], g0);
            atomicAdd(&s_imp[topi[1]], g1);
            atomicAdd(&s_imp[topi[2]], g2);
            atomicAdd(&s_imp[topi[3]], g3);
        }
        double thr_out = topv[3];   // 4th largest
        double thr_in  = topv[4];   // 5th largest
#pragma unroll
        for (int j = 0; j < 4; ++j) {
            double thr = (ny[j] > thr_in) ? thr_in : thr_out;
            float  zz  = (float)((acc_c[q][j] - thr) / sd[j]);
            loadacc[j] += 0.5f * (1.0f + erff(zz * 0.70710678118654752f));
        }
    }
#pragma unroll
    for (int j = 0; j < 4; ++j) atomicAdd(&s_load[4 * te + j], loadacc[j]);
    __syncthreads();
    if (t < E_) {
        atomicAdd(&g_imp[t],  s_imp[t]);
        atomicAdd(&g_load[t], s_load[t]);
    }

    // ---- phase B: out[b,:] = sum_k g_k * ctx[idx_k,:]  (write-bound) ----
    for (int li = 0; li < 64; ++li) {
        int   i0 = s_idx[li][0], i1 = s_idx[li][1], i2 = s_idx[li][2], i3 = s_idx[li][3];
        float gg0 = s_g[li][0], gg1 = s_g[li][1], gg2 = s_g[li][2], gg3 = s_g[li][3];
        const f32x4* c0 = (const f32x4*)&ctx[(size_t)i0 * H_];
        const f32x4* c1 = (const f32x4*)&ctx[(size_t)i1 * H_];
        const f32x4* c2 = (const f32x4*)&ctx[(size_t)i2 * H_];
        const f32x4* c3 = (const f32x4*)&ctx[(size_t)i3 * H_];
        f32x4* ob = (f32x4*)&out[(size_t)(b0 + li) * H_];
        for (int f = t; f < H4_; f += 256) {
            f32x4 a = c0[f], b4 = c1[f], c = c2[f], d4 = c3[f];
            f32x4 r = gg0 * a + gg1 * b4 + gg2 * c + gg3 * d4;
            __builtin_nontemporal_store(r, &ob[f]);   // write-once, don't pollute L2
        }
    }
}

__global__ void loss_kernel(const float* __restrict__ g_imp,
                            const float* __restrict__ g_load,
                            float* __restrict__ out)
{
    int e = threadIdx.x;   // 64 threads
    double vi = (double)g_imp[e];
    double vl = (double)g_load[e];
    double si = vi, sl = vl;
#pragma unroll
    for (int off = 1; off < 64; off <<= 1) {
        si += __shfl_xor(si, off, 64);
        sl += __shfl_xor(sl, off, 64);
    }
    double mi = si / 64.0, ml = sl / 64.0;
    double di = vi - mi, dl = vl - ml;
    double qi = di * di, ql = dl * dl;
#pragma unroll
    for (int off = 1; off < 64; off <<= 1) {
        qi += __shfl_xor(qi, off, 64);
        ql += __shfl_xor(ql, off, 64);
    }
    double vari = qi / 64.0, varl = ql / 64.0;
    double cv2i = vari / (mi * mi + 1e-10);
    double cv2l = varl / (ml * ml + 1e-10);
    if (e == 0) out[(size_t)B_ * H_] = (float)((cv2i + cv2l) * 0.01);
}

extern "C" void kernel_launch(void* const* d_in, const int* in_sizes, int n_in,
                              void* d_out, int out_size, void* d_ws, size_t ws_size,
                              hipStream_t stream)
{
    const float* x      = (const float*)d_in[0];
    const float* wgate  = (const float*)d_in[1];
    const float* wnoise = (const float*)d_in[2];
    const float* noise  = (const float*)d_in[3];
    const float* ctx    = (const float*)d_in[4];
    float* out    = (float*)d_out;
    float* g_imp  = (float*)d_ws;
    float* g_load = g_imp + E_;

    (void)hipMemsetAsync(d_ws, 0, 2 * E_ * sizeof(float), stream);
    gate_out_kernel<<<B_ / 64, 256, 0, stream>>>(x, wgate, wnoise, noise, ctx,
                                                 out, g_imp, g_load);
    loss_kernel<<<1, 64, 0, stream>>>(g_imp, g_load, out);
}